// Round 8
// baseline (165.228 us; speedup 1.0000x reference)
//
#include <hip/hip_runtime.h>

#define CIN    256
#define COUT   256
#define PTOT   4096
#define BN     64     // pixels per block; block = 256 o x 64 p, 8 waves

typedef __attribute__((ext_vector_type(8)))  short bfrag;
typedef __attribute__((ext_vector_type(16))) float f32x16;

// Hardware RNE f32->bf16 pair convert (gfx950 v_cvt_pk_bf16_f32).
// Not volatile: pure op, let the scheduler move it.
__device__ __forceinline__ unsigned int cvt_pk(float lo, float hi) {
    unsigned int r;
    asm("v_cvt_pk_bf16_f32 %0, %1, %2" : "=v"(r) : "v"(lo), "v"(hi));
    return r;
}

union FragU { unsigned int u[4]; bfrag f; };

__device__ __forceinline__ bfrag mk_fragA(const float4 lo, const float4 hi) {
    FragU r;
    r.u[0] = cvt_pk(lo.x, lo.y);
    r.u[1] = cvt_pk(lo.z, lo.w);
    r.u[2] = cvt_pk(hi.x, hi.y);
    r.u[3] = cvt_pk(hi.z, hi.w);
    return r.f;
}
__device__ __forceinline__ bfrag mk_fragB(const float* bb) {
    FragU r;
    r.u[0] = cvt_pk(bb[0], bb[1]);
    r.u[1] = cvt_pk(bb[2], bb[3]);
    r.u[2] = cvt_pk(bb[4], bb[5]);
    r.u[3] = cvt_pk(bb[6], bb[7]);
    return r.f;
}

__device__ __forceinline__ f32x16 zero16() {
    f32x16 v;
    #pragma unroll
    for (int i = 0; i < 16; ++i) v[i] = 0.0f;
    return v;
}

// LDS-free streaming GEMM: per-wave 64o x 32p output tile, K chunked by 16
// (one 32x32x16 MFMA pair per chunk). No __shared__, no barriers — LDS gave
// only 2x reuse here while the real reuse (weight x64 p-tiles, x across
// o-groups) is served by L1/L2. Waves are fully independent; latency is
// hidden by 16 waves/CU each holding a 2-deep load pipeline (~96 KB/CU in
// flight vs ~9 KB needed at 6.3 TB/s share).
__global__ __launch_bounds__(512, 4)
void selconv_direct(const float* __restrict__ x,
                    const int*   __restrict__ classes,
                    const float* __restrict__ weight,
                    const float* __restrict__ bias,
                    float*       __restrict__ out)
{
    // XCD-aware bijective swizzle (2048 % 8 == 0), sample-major within XCD:
    // the 64 p-tiles of one sample run on one XCD -> 256 KB weight slice is
    // L2-resident; x bytes belong to exactly ONE block (BM=256 covers all o).
    const int b     = blockIdx.x;              // 0..2047
    const int xcd   = b & 7;
    const int local = b >> 3;                  // 0..255
    const int n     = xcd * 4 + (local >> 6);  // 0..31
    const int p0    = (local & 63) * BN;

    const int tid  = threadIdx.x;
    const int lane = tid & 63;
    const int wid  = tid >> 6;     // 0..7
    const int wr   = wid >> 1;     // 0..3: o-group (64 rows)
    const int wc   = wid & 1;      // 0..1: p-group (32 cols)

    const int fr = lane & 31;              // row/col within 32x32 frag
    const int kh = (lane >> 5) * 8;        // 8 consecutive k per lane; same
                                           // mapping for A and B -> k-perm cancels

    const int cls = classes[n];
    const float* Wn  = weight + (size_t)cls * (COUT * CIN);
    const float* Xc  = x + (size_t)n * (CIN * PTOT) + p0 + wc * 32 + fr;
    const float* A0p = Wn + (size_t)(wr * 64 + fr) * CIN + kh;   // rows wr*64+fr
    const float* A1p = A0p + 32 * CIN;                           // rows +32

    f32x16 acc0 = zero16(), acc1 = zero16();

    // 2-deep named stages (rule #20: all indices compile-time after unroll).
    float4 a0l0, a0h0, a1l0, a1h0, a0l1, a0h1, a1l1, a1h1;
    float  bb0[8], bb1[8];

    auto loadS = [&](float4& p, float4& q, float4& r_, float4& s_,
                     float (&bb)[8], int c) {
        const int k0 = c * 16;
        // A: 16B/lane at 1KB row stride; the kh=0/kh=8 half-waves use the low/
        // high halves of the SAME 64B line -> weight lines fetched exactly once.
        p  = *(const float4*)(A0p + k0);
        q  = *(const float4*)(A0p + k0 + 4);
        r_ = *(const float4*)(A1p + k0);
        s_ = *(const float4*)(A1p + k0 + 4);
        // B: per load instr, half-wave reads 128B contiguous of row k -> coalesced.
        #pragma unroll
        for (int j = 0; j < 8; ++j)
            bb[j] = Xc[(k0 + kh + j) * PTOT];
    };

    loadS(a0l0, a0h0, a1l0, a1h0, bb0, 0);
    #pragma unroll
    for (int c = 0; c < 16; c += 2) {
        loadS(a0l1, a0h1, a1l1, a1h1, bb1, c + 1);
        {
            const bfrag bf = mk_fragB(bb0);
            acc0 = __builtin_amdgcn_mfma_f32_32x32x16_bf16(mk_fragA(a0l0, a0h0), bf, acc0, 0, 0, 0);
            acc1 = __builtin_amdgcn_mfma_f32_32x32x16_bf16(mk_fragA(a1l0, a1h0), bf, acc1, 0, 0, 0);
        }
        if (c + 2 < 16) loadS(a0l0, a0h0, a1l0, a1h0, bb0, c + 2);
        {
            const bfrag bf = mk_fragB(bb1);
            acc0 = __builtin_amdgcn_mfma_f32_32x32x16_bf16(mk_fragA(a0l1, a0h1), bf, acc0, 0, 0, 0);
            acc1 = __builtin_amdgcn_mfma_f32_32x32x16_bf16(mk_fragA(a1l1, a1h1), bf, acc1, 0, 0, 0);
        }
    }

    // epilogue: D col = lane&31 (= fr), row = (reg&3) + 8*(reg>>2) + 4*(lane>>5)
    const float* bp = bias + cls * COUT;
    float* On = out + (size_t)n * (COUT * PTOT) + p0 + wc * 32 + fr;
    const int rh = (lane >> 5) * 4;
    const int ob = wr * 64;
    #pragma unroll
    for (int r = 0; r < 16; ++r) {
        const int row = (r & 3) + 8 * (r >> 2) + rh;
        const int o0r = ob + row;
        On[(size_t)o0r * PTOT]        = acc0[r] + bp[o0r];
        On[(size_t)(o0r + 32) * PTOT] = acc1[r] + bp[o0r + 32];
    }
}

extern "C" void kernel_launch(void* const* d_in, const int* in_sizes, int n_in,
                              void* d_out, int out_size, void* d_ws, size_t ws_size,
                              hipStream_t stream) {
    const float* x       = (const float*)d_in[0];
    const int*   classes = (const int*)d_in[1];
    const float* weight  = (const float*)d_in[2];
    const float* bias    = (const float*)d_in[3];
    float*       out     = (float*)d_out;

    const int grid = 32 * (PTOT / BN);   // 2048 blocks of 512 threads
    selconv_direct<<<grid, 512, 0, stream>>>(x, classes, weight, bias, out);
}

// Round 9
// 65.659 us; speedup vs baseline: 2.5165x; 2.5165x over previous
//
#include <hip/hip_runtime.h>

#define CIN    256
#define COUT   256
#define PTOT   4096
#define BM     128
#define BN     128
#define BK     32
#define KSTEPS 8
#define LDSA   40    // A row stride in bf16: 32 data + 8 pad -> 80 B rows
#define BPADU  1024  // +4KB/buffer on B: LDS total 45.5 KB -> max 3 blocks/CU
                     // (4 blk/CU thrashes L2+L3: R3/R5 fetch 258-310 MB, 225 us)

typedef __attribute__((ext_vector_type(8)))  short bfrag;
typedef __attribute__((ext_vector_type(16))) float f32x16;

union U4F { uint4 u; bfrag f; };

// Hardware RNE f32->bf16 pair convert (verified bit-identical absmax in R8).
__device__ __forceinline__ unsigned int cvt_pk(float lo, float hi) {
    unsigned int r;
    asm("v_cvt_pk_bf16_f32 %0, %1, %2" : "=v"(r) : "v"(lo), "v"(hi));
    return r;
}

__device__ __forceinline__ f32x16 zero16() {
    f32x16 v;
    #pragma unroll
    for (int i = 0; i < 16; ++i) v[i] = 0.0f;
    return v;
}

// Counted barrier (R7): only LDS visibility is needed at the block barrier;
// global prefetch loads stay in flight across it (compiler emits counted
// vmcnt before the staged registers are consumed).
__device__ __forceinline__ void lds_barrier() {
    asm volatile("s_waitcnt lgkmcnt(0)" ::: "memory");
    __builtin_amdgcn_s_barrier();
    asm volatile("" ::: "memory");
}

// 512-thread blocks: 8 thin waves (32o x 64p each, 2 frags, 32 acc regs) so
// per-lane register total lands <= 85 -> 6 waves/SIMD -> 3 blocks x 8 waves
// = 24 waves/CU (R6/R7 ran at only 8: VGPR80+AGPR64 = 144/lane -> 2 blocks).
__global__ __launch_bounds__(512, 4)
void selconv_mfma(const float* __restrict__ x,
                  const int*   __restrict__ classes,
                  const float* __restrict__ weight,
                  const float* __restrict__ bias,
                  float*       __restrict__ out)
{
    // A: bf16 [128 rows][40]      -> 10240 B per buffer
    // B: uint k-pair [16][128 px] ->  8192 B (+4KB pad) per buffer
    __shared__ __align__(16) unsigned short As[2][BM * LDSA];
    __shared__ __align__(16) unsigned int   Bs[2][(BK / 2) * BN + BPADU];
    __shared__ float bias_s[BM];    // total 45568 B -> exactly 3 blocks/CU

    // XCD-aware bijective swizzle (2048 % 8 == 0), twin (o-half) in bit 0 so
    // the two blocks sharing an x pixel-tile are co-resident (R6-proven).
    const int b     = blockIdx.x;
    const int xcd   = b & 7;
    const int local = b >> 3;                  // 0..255
    const int n     = xcd * 4 + (local >> 6);  // 0..31
    const int o0    = (local & 1) * BM;        // twin bit
    const int p0    = ((local >> 1) & 31) * BN;

    const int tid  = threadIdx.x;
    const int lane = tid & 63;
    const int wid  = tid >> 6;                // 0..7
    const int wr   = wid >> 1;                // 0..3: o-group (32 rows)
    const int wc   = wid & 1;                 // 0..1: p-group (64 cols)

    const int cls = classes[n];
    const float* Wn = weight + (size_t)cls * (COUT * CIN) + (size_t)o0 * CIN;
    const float* Xn = x   + (size_t)n * (CIN * PTOT) + p0;
    float*       On = out + (size_t)n * (COUT * PTOT) + (size_t)o0 * PTOT + p0;

    if (tid < BM) bias_s[tid] = bias[cls * COUT + o0 + tid];

    // staging maps (512 threads)
    const int a_row = tid >> 2;           // 0..127: one row per 4 threads
    const int a_col = (tid & 3) * 8;      // 8 k per thread
    const int b_kp  = tid >> 5;           // k-pair row 0..15
    const int b_p4  = (tid & 31) * 4;     // 4 pixels; 32 lanes cover 128 contiguously

    // 2-deep named prefetch stages (rule #20: constant indices only)
    float4 Aa0, Ab0, Aa1, Ab1;            // stage0/1: A lo/hi float4
    float4 Be0, Bo0, Be1, Bo1;            // stage0/1: B even/odd k-row

    auto load0 = [&](int t) {
        const int k0 = t * BK;
        Aa0 = *(const float4*)(Wn + (size_t)a_row * CIN + k0 + a_col);
        Ab0 = *(const float4*)(Wn + (size_t)a_row * CIN + k0 + a_col + 4);
        const int kr = k0 + 2 * b_kp;
        Be0 = *(const float4*)(Xn + (size_t)kr       * PTOT + b_p4);
        Bo0 = *(const float4*)(Xn + (size_t)(kr + 1) * PTOT + b_p4);
    };
    auto load1 = [&](int t) {
        const int k0 = t * BK;
        Aa1 = *(const float4*)(Wn + (size_t)a_row * CIN + k0 + a_col);
        Ab1 = *(const float4*)(Wn + (size_t)a_row * CIN + k0 + a_col + 4);
        const int kr = k0 + 2 * b_kp;
        Be1 = *(const float4*)(Xn + (size_t)kr       * PTOT + b_p4);
        Bo1 = *(const float4*)(Xn + (size_t)(kr + 1) * PTOT + b_p4);
    };
    auto writeT = [&](int buf, const float4& Aa, const float4& Ab,
                      const float4& Be, const float4& Bo) {
        uint4 wa;                          // one 16B conflict-light A write
        wa.x = cvt_pk(Aa.x, Aa.y);
        wa.y = cvt_pk(Aa.z, Aa.w);
        wa.z = cvt_pk(Ab.x, Ab.y);
        wa.w = cvt_pk(Ab.z, Ab.w);
        *(uint4*)(&As[buf][a_row * LDSA + a_col]) = wa;
        uint4 wb;                          // low16 = even k, high16 = odd k
        wb.x = cvt_pk(Be.x, Bo.x);
        wb.y = cvt_pk(Be.y, Bo.y);
        wb.z = cvt_pk(Be.z, Bo.z);
        wb.w = cvt_pk(Be.w, Bo.w);
        *(uint4*)(&Bs[buf][b_kp * BN + b_p4]) = wb;   // 16B contiguous, conflict-free
    };

    const int fr = lane & 31;             // row/col within 32x32 frag
    const int kh = (lane >> 5) * 8;       // 8 consecutive k per lane; identical
                                          // mapping for A and B -> hw k-perm cancels
    f32x16 acc0 = zero16(), acc1 = zero16();

    auto mfma_step = [&](int buf) {
        const unsigned short* Abase = As[buf];
        const unsigned int*   Bbase = Bs[buf];
        const int rowA = wr * 32 + fr;
        const int pB0  = wc * 64 + fr;
        #pragma unroll
        for (int s = 0; s < 2; ++s) {
            const int kof = s * 16 + kh;
            const int kp0 = kof >> 1;     // k-pair row base (4 consecutive rows)
            bfrag a = *(const bfrag*)(&Abase[rowA * LDSA + kof]);
            U4F ub0, ub1;
            ub0.u.x = Bbase[(kp0 + 0) * BN + pB0];
            ub0.u.y = Bbase[(kp0 + 1) * BN + pB0];
            ub0.u.z = Bbase[(kp0 + 2) * BN + pB0];
            ub0.u.w = Bbase[(kp0 + 3) * BN + pB0];
            ub1.u.x = Bbase[(kp0 + 0) * BN + pB0 + 32];
            ub1.u.y = Bbase[(kp0 + 1) * BN + pB0 + 32];
            ub1.u.z = Bbase[(kp0 + 2) * BN + pB0 + 32];
            ub1.u.w = Bbase[(kp0 + 3) * BN + pB0 + 32];
            acc0 = __builtin_amdgcn_mfma_f32_32x32x16_bf16(a, ub0.f, acc0, 0, 0, 0);
            acc1 = __builtin_amdgcn_mfma_f32_32x32x16_bf16(a, ub1.f, acc1, 0, 0, 0);
        }
    };

    // ---- 2-deep pipeline: loads for t+2 issued at step t; loads survive the
    // ---- counted barrier -> continuous HBM MLP across 24 waves/CU.
    load0(0);
    load1(1);
    writeT(0, Aa0, Ab0, Be0, Bo0);
    lds_barrier();

    #pragma unroll
    for (int t = 0; t < KSTEPS; t += 2) {
        if (t + 2 < KSTEPS) load0(t + 2);
        mfma_step(0);
        writeT(1, Aa1, Ab1, Be1, Bo1);
        lds_barrier();
        if (t + 3 < KSTEPS) load1(t + 3);
        mfma_step(1);
        if (t + 2 < KSTEPS) { writeT(0, Aa0, Ab0, Be0, Bo0); lds_barrier(); }
    }

    // epilogue: D col = lane&31, row = (reg&3) + 8*(reg>>2) + 4*(lane>>5)
    const int col = wc * 64 + (lane & 31);
    const int rh  = (lane >> 5) * 4;
    #pragma unroll
    for (int r = 0; r < 16; ++r) {
        const int row = (r & 3) + 8 * (r >> 2) + rh;
        const int o   = wr * 32 + row;
        On[(size_t)o * PTOT + col]      = acc0[r] + bias_s[o];
        On[(size_t)o * PTOT + col + 32] = acc1[r] + bias_s[o];
    }
}

extern "C" void kernel_launch(void* const* d_in, const int* in_sizes, int n_in,
                              void* d_out, int out_size, void* d_ws, size_t ws_size,
                              hipStream_t stream) {
    const float* x       = (const float*)d_in[0];
    const int*   classes = (const int*)d_in[1];
    const float* weight  = (const float*)d_in[2];
    const float* bias    = (const float*)d_in[3];
    float*       out     = (float*)d_out;

    const int grid = 32 * (COUT / BM) * (PTOT / BN);  // 2048 blocks of 512
    selconv_mfma<<<grid, 512, 0, stream>>>(x, classes, weight, bias, out);
}